// Round 1
// baseline (182.929 us; speedup 1.0000x reference)
//
#include <hip/hip_runtime.h>
#include <stdint.h>

typedef unsigned short u16;
typedef unsigned int u32;

#define B_    32
#define S_    64
#define H_    512
#define ATT_  128
#define NWIN  2016
#define NLEV  7

typedef __bf16 bf16x8 __attribute__((ext_vector_type(8)));
typedef float  f32x4  __attribute__((ext_vector_type(4)));

__device__ __forceinline__ float bf2f(u16 u) {
  union { u32 i; float f; } v; v.i = ((u32)u) << 16; return v.f;
}
__device__ __forceinline__ u16 f2bf(float f) {
  union { float f; u32 i; } v; v.f = f;
  u32 i = v.i;
  i += 0x7fffu + ((i >> 16) & 1u);   // RNE
  return (u16)(i >> 16);
}
__device__ __forceinline__ u32 bfmax2(u32 a, u32 b) {
  u16 a0 = (u16)(a & 0xffffu), a1 = (u16)(a >> 16);
  u16 b0 = (u16)(b & 0xffffu), b1 = (u16)(b >> 16);
  u16 m0 = (bf2f(a0) >= bf2f(b0)) ? a0 : b0;
  u16 m1 = (bf2f(a1) >= bf2f(b1)) ? a1 : b1;
  return (u32)m0 | ((u32)m1 << 16);
}
__device__ __forceinline__ uint4 bfmax8(uint4 a, uint4 b) {
  uint4 m;
  m.x = bfmax2(a.x, b.x); m.y = bfmax2(a.y, b.y);
  m.z = bfmax2(a.z, b.z); m.w = bfmax2(a.w, b.w);
  return m;
}

// ---------------- k0: window index table + W1^T bf16 ----------------
// widx16[n] = s | (e2<<6) | (k<<12); w1t[n*512 + k] = bf16(W1[k*128 + n])
__launch_bounds__(256)
__global__ void k0_init(const float* __restrict__ W1, u16* __restrict__ w1t,
                        u16* __restrict__ widx) {
  int tid = threadIdx.x;
  if (blockIdx.x == 0) {
    for (int n = tid; n < NWIN; n += 256) {
      int w = 2, rem = n;
      while (rem >= 65 - w) { rem -= 65 - w; ++w; }
      int s = rem;
      int k = 31 - __clz(w);
      int e2 = s + w - (1 << k);
      widx[n] = (u16)(s | (e2 << 6) | (k << 12));
    }
  }
  int gid = blockIdx.x * 256 + tid;
  for (int idx = gid; idx < H_ * ATT_; idx += 64 * 256) {
    int n = idx >> 9, kq = idx & 511;
    w1t[idx] = f2bf(W1[kq * ATT_ + n]);
  }
}

// ---------------- k1: per-batch sparse max table (bf16, 7 levels) ----------------
__launch_bounds__(256)
__global__ void k1_table(const float* __restrict__ lstm, u16* __restrict__ table) {
  int b = blockIdx.x, tid = threadIdx.x;
  const float* src = lstm + (size_t)b * S_ * H_;
  u16* tb = table + (size_t)b * NLEV * S_ * H_;
  // level 0: fp32 -> bf16
  for (int t = tid; t < S_ * H_ / 4; t += 256) {
    float4 f = reinterpret_cast<const float4*>(src)[t];
    ushort4 u;
    u.x = f2bf(f.x); u.y = f2bf(f.y); u.z = f2bf(f.z); u.w = f2bf(f.w);
    reinterpret_cast<ushort4*>(tb)[t] = u;
  }
  // levels 1..6
  for (int k = 1; k < NLEV; ++k) {
    __syncthreads();
    int half = 1 << (k - 1);
    const u16* prev = tb + (k - 1) * S_ * H_;
    u16* cur = tb + k * S_ * H_;
    for (int t = tid; t < S_ * H_ / 8; t += 256) {  // 4096 chunks of 8 bf16
      int r = t >> 6, c = t & 63;
      int r2 = r + half; if (r2 > S_ - 1) r2 = S_ - 1;  // garbage region never read
      uint4 a = *reinterpret_cast<const uint4*>(prev + r * H_ + c * 8);
      uint4 bq = *reinterpret_cast<const uint4*>(prev + r2 * H_ + c * 8);
      uint4 m = bfmax8(a, bq);
      *reinterpret_cast<uint4*>(cur + r * H_ + c * 8) = m;
    }
  }
}

// ---------------- k2: pooled @ W1 (MFMA bf16) + bias + relu + @W2 -> scores ----------------
// grid (21, 32), 256 thr. Tile: 96 windows x 128 att, K=512 in chunks of 64.
__launch_bounds__(256)
__global__ void k2_scores(const u16* __restrict__ table, const u16* __restrict__ w1t,
                          const float* __restrict__ b1, const float* __restrict__ w2,
                          const u16* __restrict__ widx, float* __restrict__ scores) {
  const int b = blockIdx.y, mt = blockIdx.x;
  __shared__ u16 As[96 * 72];    // pooled tile, row stride 72 (pad 8) bf16
  __shared__ u16 Bs[128 * 72];   // W1^T tile
  __shared__ u16 widx_l[96];
  __shared__ float b1s[128], w2s[128], sc[96];
  int tid = threadIdx.x;
  if (tid < 96) { widx_l[tid] = widx[mt * 96 + tid]; sc[tid] = 0.f; }
  if (tid < 128) { b1s[tid] = b1[tid]; w2s[tid] = w2[tid]; }
  __syncthreads();

  const u16* tb = table + (size_t)b * NLEV * S_ * H_;
  int wid = tid >> 6, lane = tid & 63;
  int wm = wid & 1, wn = wid >> 1;
  int lrow = lane & 15, quad = lane >> 4;

  f32x4 acc[3][4];
#pragma unroll
  for (int i = 0; i < 3; ++i)
#pragma unroll
    for (int j = 0; j < 4; ++j) acc[i][j] = (f32x4){0.f, 0.f, 0.f, 0.f};

  for (int kk = 0; kk < H_; kk += 64) {
    // stage A: 96 rows x 8 chunks (8 bf16 each) = 768 tasks
    for (int t = tid; t < 768; t += 256) {
      int r = t >> 3, c = t & 7;
      int pk = widx_l[r];
      int s = pk & 63, e2 = (pk >> 6) & 63, lv = pk >> 12;
      uint4 va = *reinterpret_cast<const uint4*>(tb + (lv * S_ + s) * H_ + kk + c * 8);
      uint4 vb = *reinterpret_cast<const uint4*>(tb + (lv * S_ + e2) * H_ + kk + c * 8);
      uint4 vm = bfmax8(va, vb);
      *reinterpret_cast<uint4*>(&As[r * 72 + c * 8]) = vm;
    }
    // stage B: 128 rows x 8 chunks = 1024 tasks
    for (int t = tid; t < 1024; t += 256) {
      int n = t >> 3, c = t & 7;
      uint4 v = *reinterpret_cast<const uint4*>(w1t + n * H_ + kk + c * 8);
      *reinterpret_cast<uint4*>(&Bs[n * 72 + c * 8]) = v;
    }
    __syncthreads();
#pragma unroll
    for (int ks = 0; ks < 64; ks += 32) {
      bf16x8 af[3], bfr[4];
#pragma unroll
      for (int i = 0; i < 3; ++i)
        af[i] = *reinterpret_cast<const bf16x8*>(&As[(wm * 48 + i * 16 + lrow) * 72 + ks + quad * 8]);
#pragma unroll
      for (int j = 0; j < 4; ++j)
        bfr[j] = *reinterpret_cast<const bf16x8*>(&Bs[(wn * 64 + j * 16 + lrow) * 72 + ks + quad * 8]);
#pragma unroll
      for (int i = 0; i < 3; ++i)
#pragma unroll
        for (int j = 0; j < 4; ++j)
          acc[i][j] = __builtin_amdgcn_mfma_f32_16x16x32_bf16(af[i], bfr[j], acc[i][j], 0, 0, 0);
    }
    __syncthreads();
  }

  // epilogue: score[m] = sum_n relu(hid + b1) * w2  (b2 dropped: softmax shift-invariant)
#pragma unroll
  for (int i = 0; i < 3; ++i) {
#pragma unroll
    for (int r = 0; r < 4; ++r) {
      float p = 0.f;
#pragma unroll
      for (int j = 0; j < 4; ++j) {
        int n = wn * 64 + j * 16 + lrow;
        float v = acc[i][j][r] + b1s[n];
        p += (v > 0.f ? v : 0.f) * w2s[n];
      }
      p += __shfl_xor(p, 1, 16);
      p += __shfl_xor(p, 2, 16);
      p += __shfl_xor(p, 4, 16);
      p += __shfl_xor(p, 8, 16);
      if (lrow == 0) atomicAdd(&sc[wm * 48 + i * 16 + quad * 4 + r], p);
    }
  }
  __syncthreads();
  if (tid < 96) scores[b * NWIN + mt * 96 + tid] = sc[tid];
}

// ---------------- k3: softmax over 2016 per batch ----------------
__launch_bounds__(256)
__global__ void k3_softmax(const float* __restrict__ scores, float* __restrict__ attn) {
  int b = blockIdx.x, tid = threadIdx.x;
  __shared__ float red[256];
  float mx = -1e30f;
  for (int n = tid; n < NWIN; n += 256) mx = fmaxf(mx, scores[b * NWIN + n]);
  red[tid] = mx; __syncthreads();
  for (int s = 128; s > 0; s >>= 1) {
    if (tid < s) red[tid] = fmaxf(red[tid], red[tid + s]);
    __syncthreads();
  }
  mx = red[0]; __syncthreads();
  float sum = 0.f;
  for (int n = tid; n < NWIN; n += 256) {
    float e = __expf(scores[b * NWIN + n] - mx);
    attn[b * NWIN + n] = e;
    sum += e;
  }
  red[tid] = sum; __syncthreads();
  for (int s = 128; s > 0; s >>= 1) {
    if (tid < s) red[tid] += red[tid + s];
    __syncthreads();
  }
  float inv = 1.f / red[0];
  __syncthreads();
  for (int n = tid; n < NWIN; n += 256) attn[b * NWIN + n] *= inv;
}

// ---------------- k4: out[b,h] = sum_n attn * pooled ----------------
// grid (16, 32), 256 thr; 32-wide h slice; table levels 1..6 staged in LDS.
__launch_bounds__(256)
__global__ void k4_out(const u16* __restrict__ table, const float* __restrict__ attn,
                       const u16* __restrict__ widx, float* __restrict__ out) {
  int hc = blockIdx.x, b = blockIdx.y, tid = threadIdx.x;
  __shared__ u16 Tl[6 * 64 * 32];       // 48 KB
  __shared__ float attn_l[NWIN];        // 8 KB
  __shared__ u16 widx_l[NWIN];          // 4 KB
  __shared__ float red[8][32];
  const u16* tb = table + (size_t)b * NLEV * S_ * H_ + S_ * H_;  // skip level 0
  int h0 = hc * 32;
  for (int t = tid; t < 6 * 64 * 4; t += 256) {   // 1536 tasks, 8 bf16 each
    int row = t >> 2, c = t & 3;
    uint4 v = *reinterpret_cast<const uint4*>(tb + row * H_ + h0 + c * 8);
    *reinterpret_cast<uint4*>(&Tl[row * 32 + c * 8]) = v;
  }
  for (int n = tid; n < NWIN; n += 256) {
    attn_l[n] = attn[b * NWIN + n];
    widx_l[n] = widx[n];
  }
  __syncthreads();
  int h = tid & 31, g = tid >> 5;   // 8 groups x 252 windows
  float acc = 0.f;
  for (int n = g * 252; n < g * 252 + 252; ++n) {
    int pk = widx_l[n];
    int s = pk & 63, e2 = (pk >> 6) & 63, lv = pk >> 12;
    float va = bf2f(Tl[((lv - 1) * 64 + s) * 32 + h]);
    float vb = bf2f(Tl[((lv - 1) * 64 + e2) * 32 + h]);
    acc += attn_l[n] * fmaxf(va, vb);
  }
  red[g][h] = acc;
  __syncthreads();
  if (tid < 32) {
    float sum = 0.f;
#pragma unroll
    for (int g2 = 0; g2 < 8; ++g2) sum += red[g2][tid];
    out[b * H_ + h0 + tid] = sum;
  }
}

// ---------------- launch ----------------
extern "C" void kernel_launch(void* const* d_in, const int* in_sizes, int n_in,
                              void* d_out, int out_size, void* d_ws, size_t ws_size,
                              hipStream_t stream) {
  const float* lstm = (const float*)d_in[0];
  const float* W1   = (const float*)d_in[1];
  const float* b1   = (const float*)d_in[2];
  const float* W2   = (const float*)d_in[3];
  // d_in[4] = b2: constant shift before softmax -> no effect, unused.
  float* out = (float*)d_out;

  char* ws = (char*)d_ws;
  // layout: widx16 [0,4096) | w1t bf16 [4096, 4096+131072) | table bf16 (14.7MB)
  //         | scores (258048) | attn (258048)   total ~14.6 MiB
  u16*   widx   = (u16*)(ws + 0);
  u16*   w1t    = (u16*)(ws + 4096);
  u16*   table  = (u16*)(ws + 135168);
  float* scores = (float*)(ws + 14815232);
  float* attn   = (float*)(ws + 15073280);

  k0_init   <<<64, 256, 0, stream>>>(W1, w1t, widx);
  k1_table  <<<B_, 256, 0, stream>>>(lstm, table);
  k2_scores <<<dim3(21, B_), 256, 0, stream>>>(table, w1t, b1, W2, widx, scores);
  k3_softmax<<<B_, 256, 0, stream>>>(scores, attn);
  k4_out    <<<dim3(16, B_), 256, 0, stream>>>(table, attn, widx, out);
}

// Round 2
// 133.588 us; speedup vs baseline: 1.3694x; 1.3694x over previous
//
#include <hip/hip_runtime.h>
#include <stdint.h>

typedef unsigned short u16;
typedef unsigned int u32;

#define B_    32
#define S_    64
#define H_    512
#define ATT_  128
#define NWIN  2016
#define NLEV  7

typedef __bf16 bf16x8 __attribute__((ext_vector_type(8)));
typedef float  f32x4  __attribute__((ext_vector_type(4)));

__device__ __forceinline__ float bf2f(u16 u) {
  union { u32 i; float f; } v; v.i = ((u32)u) << 16; return v.f;
}
__device__ __forceinline__ u16 f2bf(float f) {
  union { float f; u32 i; } v; v.f = f;
  u32 i = v.i;
  i += 0x7fffu + ((i >> 16) & 1u);   // RNE
  return (u16)(i >> 16);
}
__device__ __forceinline__ u32 bfmax2(u32 a, u32 b) {
  u16 a0 = (u16)(a & 0xffffu), a1 = (u16)(a >> 16);
  u16 b0 = (u16)(b & 0xffffu), b1 = (u16)(b >> 16);
  u16 m0 = (bf2f(a0) >= bf2f(b0)) ? a0 : b0;
  u16 m1 = (bf2f(a1) >= bf2f(b1)) ? a1 : b1;
  return (u32)m0 | ((u32)m1 << 16);
}
__device__ __forceinline__ uint4 bfmax8(uint4 a, uint4 b) {
  uint4 m;
  m.x = bfmax2(a.x, b.x); m.y = bfmax2(a.y, b.y);
  m.z = bfmax2(a.z, b.z); m.w = bfmax2(a.w, b.w);
  return m;
}

// ---------------- k0: window index table + W1^T bf16 ----------------
// widx16[n] = s | (e2<<6) | (k<<12); w1t[n*512 + k] = bf16(W1[k*128 + n])
__launch_bounds__(256)
__global__ void k0_init(const float* __restrict__ W1, u16* __restrict__ w1t,
                        u16* __restrict__ widx) {
  int tid = threadIdx.x;
  if (blockIdx.x == 0) {
    for (int n = tid; n < NWIN; n += 256) {
      int w = 2, rem = n;
      while (rem >= 65 - w) { rem -= 65 - w; ++w; }
      int s = rem;
      int k = 31 - __clz(w);
      int e2 = s + w - (1 << k);
      widx[n] = (u16)(s | (e2 << 6) | (k << 12));
    }
  }
  int gid = blockIdx.x * 256 + tid;
  for (int idx = gid; idx < H_ * ATT_; idx += 64 * 256) {
    int n = idx >> 9, kq = idx & 511;
    w1t[idx] = f2bf(W1[kq * ATT_ + n]);
  }
}

// ---------------- k1: sparse max table (bf16, 7 levels) ----------------
// grid (8, 32): 64-column slab per block, all levels in LDS ping-pong.
// R1 fix: was grid(32) -> 1.1% occupancy, 70 us, top dispatch. Level
// recursion is along S only; H is fully parallel -> 256 blocks.
__launch_bounds__(256)
__global__ void k1_table(const float* __restrict__ lstm, u16* __restrict__ table) {
  int hc = blockIdx.x, b = blockIdx.y, tid = threadIdx.x;
  __shared__ u16 bufA[64 * 64], bufB[64 * 64];
  const float* src = lstm + (size_t)b * S_ * H_ + hc * 64;
  u16* tb = table + (size_t)b * NLEV * S_ * H_ + hc * 64;
  // level 0: fp32 -> bf16, stash in LDS + write to global
  for (int t = tid; t < 64 * 16; t += 256) {
    int r = t >> 4, c4 = t & 15;
    float4 f = *reinterpret_cast<const float4*>(src + r * H_ + c4 * 4);
    ushort4 u;
    u.x = f2bf(f.x); u.y = f2bf(f.y); u.z = f2bf(f.z); u.w = f2bf(f.w);
    *reinterpret_cast<ushort4*>(&bufA[r * 64 + c4 * 4]) = u;
    *reinterpret_cast<ushort4*>(tb + r * H_ + c4 * 4) = u;
  }
  u16* pa = bufA; u16* pb = bufB;
  for (int k = 1; k < NLEV; ++k) {
    __syncthreads();
    int half = 1 << (k - 1);
    u16* dst_g = tb + k * S_ * H_;
    for (int t = tid; t < 64 * 16; t += 256) {
      int r = t >> 4, c4 = t & 15;
      int r2 = r + half; if (r2 > 63) r2 = 63;  // replicated tail never read
      uint2 a  = *reinterpret_cast<const uint2*>(&pa[r  * 64 + c4 * 4]);
      uint2 bq = *reinterpret_cast<const uint2*>(&pa[r2 * 64 + c4 * 4]);
      uint2 m; m.x = bfmax2(a.x, bq.x); m.y = bfmax2(a.y, bq.y);
      *reinterpret_cast<uint2*>(&pb[r * 64 + c4 * 4]) = m;
      *reinterpret_cast<uint2*>(dst_g + r * H_ + c4 * 4) = m;
    }
    u16* tmp = pa; pa = pb; pb = tmp;
  }
}

// ---------------- k2: pooled @ W1 (MFMA bf16) + bias + relu + @W2 -> scores ----------------
// grid (21, 32), 256 thr. Tile: 96 windows x 128 att, K=512 in chunks of 64.
__launch_bounds__(256)
__global__ void k2_scores(const u16* __restrict__ table, const u16* __restrict__ w1t,
                          const float* __restrict__ b1, const float* __restrict__ w2,
                          const u16* __restrict__ widx, float* __restrict__ scores) {
  const int b = blockIdx.y, mt = blockIdx.x;
  __shared__ u16 As[96 * 72];    // pooled tile, row stride 72 (pad 8) bf16
  __shared__ u16 Bs[128 * 72];   // W1^T tile
  __shared__ u16 widx_l[96];
  __shared__ float b1s[128], w2s[128], sc[96];
  int tid = threadIdx.x;
  if (tid < 96) { widx_l[tid] = widx[mt * 96 + tid]; sc[tid] = 0.f; }
  if (tid < 128) { b1s[tid] = b1[tid]; w2s[tid] = w2[tid]; }
  __syncthreads();

  const u16* tb = table + (size_t)b * NLEV * S_ * H_;
  int wid = tid >> 6, lane = tid & 63;
  int wm = wid & 1, wn = wid >> 1;
  int lrow = lane & 15, quad = lane >> 4;

  f32x4 acc[3][4];
#pragma unroll
  for (int i = 0; i < 3; ++i)
#pragma unroll
    for (int j = 0; j < 4; ++j) acc[i][j] = (f32x4){0.f, 0.f, 0.f, 0.f};

  for (int kk = 0; kk < H_; kk += 64) {
    // stage A: 96 rows x 8 chunks (8 bf16 each) = 768 tasks
    for (int t = tid; t < 768; t += 256) {
      int r = t >> 3, c = t & 7;
      int pk = widx_l[r];
      int s = pk & 63, e2 = (pk >> 6) & 63, lv = pk >> 12;
      uint4 va = *reinterpret_cast<const uint4*>(tb + (lv * S_ + s) * H_ + kk + c * 8);
      uint4 vb = *reinterpret_cast<const uint4*>(tb + (lv * S_ + e2) * H_ + kk + c * 8);
      uint4 vm = bfmax8(va, vb);
      *reinterpret_cast<uint4*>(&As[r * 72 + c * 8]) = vm;
    }
    // stage B: 128 rows x 8 chunks = 1024 tasks
    for (int t = tid; t < 1024; t += 256) {
      int n = t >> 3, c = t & 7;
      uint4 v = *reinterpret_cast<const uint4*>(w1t + n * H_ + kk + c * 8);
      *reinterpret_cast<uint4*>(&Bs[n * 72 + c * 8]) = v;
    }
    __syncthreads();
#pragma unroll
    for (int ks = 0; ks < 64; ks += 32) {
      bf16x8 af[3], bfr[4];
#pragma unroll
      for (int i = 0; i < 3; ++i)
        af[i] = *reinterpret_cast<const bf16x8*>(&As[(wm * 48 + i * 16 + lrow) * 72 + ks + quad * 8]);
#pragma unroll
      for (int j = 0; j < 4; ++j)
        bfr[j] = *reinterpret_cast<const bf16x8*>(&Bs[(wn * 64 + j * 16 + lrow) * 72 + ks + quad * 8]);
#pragma unroll
      for (int i = 0; i < 3; ++i)
#pragma unroll
        for (int j = 0; j < 4; ++j)
          acc[i][j] = __builtin_amdgcn_mfma_f32_16x16x32_bf16(af[i], bfr[j], acc[i][j], 0, 0, 0);
    }
    __syncthreads();
  }

  // epilogue: score[m] = sum_n relu(hid + b1) * w2  (b2 dropped: softmax shift-invariant)
#pragma unroll
  for (int i = 0; i < 3; ++i) {
#pragma unroll
    for (int r = 0; r < 4; ++r) {
      float p = 0.f;
#pragma unroll
      for (int j = 0; j < 4; ++j) {
        int n = wn * 64 + j * 16 + lrow;
        float v = acc[i][j][r] + b1s[n];
        p += (v > 0.f ? v : 0.f) * w2s[n];
      }
      p += __shfl_xor(p, 1, 16);
      p += __shfl_xor(p, 2, 16);
      p += __shfl_xor(p, 4, 16);
      p += __shfl_xor(p, 8, 16);
      if (lrow == 0) atomicAdd(&sc[wm * 48 + i * 16 + quad * 4 + r], p);
    }
  }
  __syncthreads();
  if (tid < 96) scores[b * NWIN + mt * 96 + tid] = sc[tid];
}

// ---------------- k3: softmax over 2016 per batch ----------------
__launch_bounds__(256)
__global__ void k3_softmax(const float* __restrict__ scores, float* __restrict__ attn) {
  int b = blockIdx.x, tid = threadIdx.x;
  __shared__ float red[256];
  float mx = -1e30f;
  for (int n = tid; n < NWIN; n += 256) mx = fmaxf(mx, scores[b * NWIN + n]);
  red[tid] = mx; __syncthreads();
  for (int s = 128; s > 0; s >>= 1) {
    if (tid < s) red[tid] = fmaxf(red[tid], red[tid + s]);
    __syncthreads();
  }
  mx = red[0]; __syncthreads();
  float sum = 0.f;
  for (int n = tid; n < NWIN; n += 256) {
    float e = __expf(scores[b * NWIN + n] - mx);
    attn[b * NWIN + n] = e;
    sum += e;
  }
  red[tid] = sum; __syncthreads();
  for (int s = 128; s > 0; s >>= 1) {
    if (tid < s) red[tid] += red[tid + s];
    __syncthreads();
  }
  float inv = 1.f / red[0];
  __syncthreads();
  for (int n = tid; n < NWIN; n += 256) attn[b * NWIN + n] *= inv;
}

// ---------------- k4: out[b,h] = sum_n attn * pooled ----------------
// grid (16, 32), 256 thr; 32-wide h slice; table levels 1..6 staged in LDS.
__launch_bounds__(256)
__global__ void k4_out(const u16* __restrict__ table, const float* __restrict__ attn,
                       const u16* __restrict__ widx, float* __restrict__ out) {
  int hc = blockIdx.x, b = blockIdx.y, tid = threadIdx.x;
  __shared__ u16 Tl[6 * 64 * 32];       // 48 KB
  __shared__ float attn_l[NWIN];        // 8 KB
  __shared__ u16 widx_l[NWIN];          // 4 KB
  __shared__ float red[8][32];
  const u16* tb = table + (size_t)b * NLEV * S_ * H_ + S_ * H_;  // skip level 0
  int h0 = hc * 32;
  for (int t = tid; t < 6 * 64 * 4; t += 256) {   // 1536 tasks, 8 bf16 each
    int row = t >> 2, c = t & 3;
    uint4 v = *reinterpret_cast<const uint4*>(tb + row * H_ + h0 + c * 8);
    *reinterpret_cast<uint4*>(&Tl[row * 32 + c * 8]) = v;
  }
  for (int n = tid; n < NWIN; n += 256) {
    attn_l[n] = attn[b * NWIN + n];
    widx_l[n] = widx[n];
  }
  __syncthreads();
  int h = tid & 31, g = tid >> 5;   // 8 groups x 252 windows
  float acc = 0.f;
  for (int n = g * 252; n < g * 252 + 252; ++n) {
    int pk = widx_l[n];
    int s = pk & 63, e2 = (pk >> 6) & 63, lv = pk >> 12;
    float va = bf2f(Tl[((lv - 1) * 64 + s) * 32 + h]);
    float vb = bf2f(Tl[((lv - 1) * 64 + e2) * 32 + h]);
    acc += attn_l[n] * fmaxf(va, vb);
  }
  red[g][h] = acc;
  __syncthreads();
  if (tid < 32) {
    float sum = 0.f;
#pragma unroll
    for (int g2 = 0; g2 < 8; ++g2) sum += red[g2][tid];
    out[b * H_ + h0 + tid] = sum;
  }
}

// ---------------- launch ----------------
extern "C" void kernel_launch(void* const* d_in, const int* in_sizes, int n_in,
                              void* d_out, int out_size, void* d_ws, size_t ws_size,
                              hipStream_t stream) {
  const float* lstm = (const float*)d_in[0];
  const float* W1   = (const float*)d_in[1];
  const float* b1   = (const float*)d_in[2];
  const float* W2   = (const float*)d_in[3];
  // d_in[4] = b2: constant shift before softmax -> no effect, unused.
  float* out = (float*)d_out;

  char* ws = (char*)d_ws;
  // layout: widx16 [0,4096) | w1t bf16 [4096, 4096+131072) | table bf16 (14.7MB)
  //         | scores (258048) | attn (258048)   total ~14.6 MiB
  u16*   widx   = (u16*)(ws + 0);
  u16*   w1t    = (u16*)(ws + 4096);
  u16*   table  = (u16*)(ws + 135168);
  float* scores = (float*)(ws + 14815232);
  float* attn   = (float*)(ws + 15073280);

  k0_init   <<<64, 256, 0, stream>>>(W1, w1t, widx);
  k1_table  <<<dim3(8, B_), 256, 0, stream>>>(lstm, table);
  k2_scores <<<dim3(21, B_), 256, 0, stream>>>(table, w1t, b1, W2, widx, scores);
  k3_softmax<<<B_, 256, 0, stream>>>(scores, attn);
  k4_out    <<<dim3(16, B_), 256, 0, stream>>>(table, attn, widx, out);
}

// Round 3
// 133.174 us; speedup vs baseline: 1.3736x; 1.0031x over previous
//
#include <hip/hip_runtime.h>
#include <stdint.h>

typedef unsigned short u16;
typedef unsigned int u32;

#define B_    32
#define S_    64
#define H_    512
#define ATT_  128
#define NWIN  2016
#define NLEV  7

typedef __bf16 bf16x8 __attribute__((ext_vector_type(8)));
typedef float  f32x4  __attribute__((ext_vector_type(4)));

__device__ __forceinline__ float asf(u32 i) {
  union { u32 i; float f; } v; v.i = i; return v.f;
}
__device__ __forceinline__ u32 asu(float f) {
  union { float f; u32 i; } v; v.f = f; return v.i;
}
__device__ __forceinline__ float bf2f(u16 u) { return asf(((u32)u) << 16); }
__device__ __forceinline__ u16 f2bf(float f) {
  u32 i = asu(f);
  i += 0x7fffu + ((i >> 16) & 1u);   // RNE
  return (u16)(i >> 16);
}
// max of two bf16x2 packed in u32. Both halves viewed as exact f32 (low bits
// zero) -> v_max_f32 is exact bf16 max; repack high halves. ~8 VALU ops
// (was ~15 with the cmp/cndmask unpack version).
__device__ __forceinline__ u32 bfmax2(u32 a, u32 b) {
  float a0 = asf(a << 16), a1 = asf(a & 0xffff0000u);
  float b0 = asf(b << 16), b1 = asf(b & 0xffff0000u);
  u32 m0 = asu(fmaxf(a0, b0)), m1 = asu(fmaxf(a1, b1));
  return (m1 & 0xffff0000u) | (m0 >> 16);
}
__device__ __forceinline__ uint4 bfmax8(uint4 a, uint4 b) {
  uint4 m;
  m.x = bfmax2(a.x, b.x); m.y = bfmax2(a.y, b.y);
  m.z = bfmax2(a.z, b.z); m.w = bfmax2(a.w, b.w);
  return m;
}

// ---------------- k01: sparse table build + widx + W1^T (merged launch) ----
// blocks 0..255: per-(hc,b) 64-col slab, 7 levels in LDS ping-pong.
// blocks 256..287: W1^T -> bf16 transpose; block 256 also emits widx.
__launch_bounds__(256)
__global__ void k01_init(const float* __restrict__ lstm, const float* __restrict__ W1,
                         u16* __restrict__ table, u16* __restrict__ w1t,
                         u16* __restrict__ widx) {
  int bid = blockIdx.x, tid = threadIdx.x;
  __shared__ u16 bufA[64 * 64], bufB[64 * 64];
  if (bid < 256) {
    int hc = bid & 7, b = bid >> 3;
    const float* src = lstm + (size_t)b * S_ * H_ + hc * 64;
    u16* tb = table + (size_t)b * NLEV * S_ * H_ + hc * 64;
    for (int t = tid; t < 64 * 16; t += 256) {
      int r = t >> 4, c4 = t & 15;
      float4 f = *reinterpret_cast<const float4*>(src + r * H_ + c4 * 4);
      ushort4 u;
      u.x = f2bf(f.x); u.y = f2bf(f.y); u.z = f2bf(f.z); u.w = f2bf(f.w);
      *reinterpret_cast<ushort4*>(&bufA[r * 64 + c4 * 4]) = u;
      *reinterpret_cast<ushort4*>(tb + r * H_ + c4 * 4) = u;
    }
    u16* pa = bufA; u16* pb = bufB;
    for (int k = 1; k < NLEV; ++k) {
      __syncthreads();
      int half = 1 << (k - 1);
      u16* dst_g = tb + k * S_ * H_;
      for (int t = tid; t < 64 * 16; t += 256) {
        int r = t >> 4, c4 = t & 15;
        int r2 = r + half; if (r2 > 63) r2 = 63;  // replicated tail never read
        uint2 a  = *reinterpret_cast<const uint2*>(&pa[r  * 64 + c4 * 4]);
        uint2 bq = *reinterpret_cast<const uint2*>(&pa[r2 * 64 + c4 * 4]);
        uint2 m; m.x = bfmax2(a.x, bq.x); m.y = bfmax2(a.y, bq.y);
        *reinterpret_cast<uint2*>(&pb[r * 64 + c4 * 4]) = m;
        *reinterpret_cast<uint2*>(dst_g + r * H_ + c4 * 4) = m;
      }
      u16* tmp = pa; pa = pb; pb = tmp;
    }
  } else {
    int gb = bid - 256;   // 0..31
    if (gb == 0) {
      for (int n = tid; n < NWIN; n += 256) {
        int w = 2, rem = n;
        while (rem >= 65 - w) { rem -= 65 - w; ++w; }
        int s = rem;
        int k = 31 - __clz(w);
        int e2 = s + w - (1 << k);
        widx[n] = (u16)(s | (e2 << 6) | (k << 12));
      }
    }
    for (int q = tid; q < 2048; q += 256) {
      int idx = gb * 2048 + q;
      int n = idx >> 9, kq = idx & 511;
      w1t[idx] = f2bf(W1[kq * ATT_ + n]);
    }
  }
}

// ---------------- k2: pooled @ W1 (MFMA bf16) + bias + relu + @W2 -> scores ----
// grid (21, 32), 256 thr. Tile: 96 windows x 128 att, K=512 in chunks of 64.
// R3: register software-pipeline — chunk kk+1's global loads issued right
// after the post-store barrier, consumed at next iteration's LDS store, so
// L2 latency overlaps the 24 MFMAs of chunk kk.
__launch_bounds__(256, 3)
__global__ void k2_scores(const u16* __restrict__ table, const u16* __restrict__ w1t,
                          const float* __restrict__ b1, const float* __restrict__ w2,
                          const u16* __restrict__ widx, float* __restrict__ scores) {
  const int b = blockIdx.y, mt = blockIdx.x;
  __shared__ u16 As[96 * 72];    // pooled tile, row stride 72 (pad 8) bf16
  __shared__ u16 Bs[128 * 72];   // W1^T tile
  __shared__ u16 widx_l[96];
  __shared__ float b1s[128], w2s[128], sc[96];
  int tid = threadIdx.x;
  if (tid < 96) { widx_l[tid] = widx[mt * 96 + tid]; sc[tid] = 0.f; }
  if (tid < 128) { b1s[tid] = b1[tid]; w2s[tid] = w2[tid]; }
  __syncthreads();

  const u16* tb = table + (size_t)b * NLEV * S_ * H_;
  // fixed per-thread staging slots: A = 3 x (2 loads), B = 4 x (1 load)
  int ar[3], ac[3];
  const u16 *apa[3], *apb[3];
#pragma unroll
  for (int i = 0; i < 3; ++i) {
    int t = tid + i * 256; ar[i] = t >> 3; ac[i] = t & 7;
    int pk = widx_l[ar[i]];
    int s = pk & 63, e2 = (pk >> 6) & 63, lv = pk >> 12;
    apa[i] = tb + (lv * S_ + s) * H_ + ac[i] * 8;
    apb[i] = tb + (lv * S_ + e2) * H_ + ac[i] * 8;
  }
  int bn[4], bc[4];
#pragma unroll
  for (int j = 0; j < 4; ++j) {
    int t = tid + j * 256; bn[j] = t >> 3; bc[j] = t & 7;
  }

  uint4 ra[3], rb[3], rB[4];
#define ISSUE(KK) do { \
  _Pragma("unroll") for (int i = 0; i < 3; ++i) { \
    ra[i] = *reinterpret_cast<const uint4*>(apa[i] + (KK)); \
    rb[i] = *reinterpret_cast<const uint4*>(apb[i] + (KK)); } \
  _Pragma("unroll") for (int j = 0; j < 4; ++j) \
    rB[j] = *reinterpret_cast<const uint4*>(w1t + bn[j] * H_ + (KK) + bc[j] * 8); \
} while (0)

  ISSUE(0);

  int wid = tid >> 6, lane = tid & 63;
  int wm = wid & 1, wn = wid >> 1;
  int lrow = lane & 15, quad = lane >> 4;

  f32x4 acc[3][4];
#pragma unroll
  for (int i = 0; i < 3; ++i)
#pragma unroll
    for (int j = 0; j < 4; ++j) acc[i][j] = (f32x4){0.f, 0.f, 0.f, 0.f};

  for (int kc = 0; kc < 8; ++kc) {
    uint4 mA[3];
#pragma unroll
    for (int i = 0; i < 3; ++i) mA[i] = bfmax8(ra[i], rb[i]);
    __syncthreads();   // all waves done MFMA-reading previous chunk
#pragma unroll
    for (int i = 0; i < 3; ++i)
      *reinterpret_cast<uint4*>(&As[ar[i] * 72 + ac[i] * 8]) = mA[i];
#pragma unroll
    for (int j = 0; j < 4; ++j)
      *reinterpret_cast<uint4*>(&Bs[bn[j] * 72 + bc[j] * 8]) = rB[j];
    __syncthreads();
    if (kc < 7) ISSUE((kc + 1) * 64);   // overlap with MFMA below
#pragma unroll
    for (int ks = 0; ks < 64; ks += 32) {
      bf16x8 af[3], bfr[4];
#pragma unroll
      for (int i = 0; i < 3; ++i)
        af[i] = *reinterpret_cast<const bf16x8*>(&As[(wm * 48 + i * 16 + lrow) * 72 + ks + quad * 8]);
#pragma unroll
      for (int j = 0; j < 4; ++j)
        bfr[j] = *reinterpret_cast<const bf16x8*>(&Bs[(wn * 64 + j * 16 + lrow) * 72 + ks + quad * 8]);
#pragma unroll
      for (int i = 0; i < 3; ++i)
#pragma unroll
        for (int j = 0; j < 4; ++j)
          acc[i][j] = __builtin_amdgcn_mfma_f32_16x16x32_bf16(af[i], bfr[j], acc[i][j], 0, 0, 0);
    }
  }
#undef ISSUE

  // epilogue: score[m] = sum_n relu(hid + b1) * w2  (b2 dropped: softmax shift-invariant)
#pragma unroll
  for (int i = 0; i < 3; ++i) {
#pragma unroll
    for (int r = 0; r < 4; ++r) {
      float p = 0.f;
#pragma unroll
      for (int j = 0; j < 4; ++j) {
        int n = wn * 64 + j * 16 + lrow;
        float v = acc[i][j][r] + b1s[n];
        p += (v > 0.f ? v : 0.f) * w2s[n];
      }
      p += __shfl_xor(p, 1, 16);
      p += __shfl_xor(p, 2, 16);
      p += __shfl_xor(p, 4, 16);
      p += __shfl_xor(p, 8, 16);
      if (lrow == 0) atomicAdd(&sc[wm * 48 + i * 16 + quad * 4 + r], p);
    }
  }
  __syncthreads();
  if (tid < 96) scores[b * NWIN + mt * 96 + tid] = sc[tid];
}

// ---------------- k34: softmax (per-block, redundant) + weighted sum ------
// grid (16, 32), 256 thr; 32-wide h slice. Softmax over scores computed
// in-block (8 exp/thread + 2 wave reductions) — removes the 32-block k3
// launch and the attn global round-trip. Normalization folded into the
// final scale (out = acc * 1/sum).
__launch_bounds__(256)
__global__ void k34_out(const u16* __restrict__ table, const float* __restrict__ scores,
                        const u16* __restrict__ widx, float* __restrict__ out) {
  int hc = blockIdx.x, b = blockIdx.y, tid = threadIdx.x;
  __shared__ u16 Tl[6 * 64 * 32];       // 24 KB, levels 1..6, 32-col slice
  __shared__ float attn_l[NWIN];        // 8 KB (exp values, unnormalized)
  __shared__ u16 widx_l[NWIN];          // 4 KB
  __shared__ float red[8][32];
  __shared__ float wredM[4], wredS[4];
  const u16* tb = table + (size_t)b * NLEV * S_ * H_ + S_ * H_;  // skip level 0
  int h0 = hc * 32;
  int lane = tid & 63, wid = tid >> 6;

  for (int t = tid; t < 6 * 64 * 4; t += 256) {
    int row = t >> 2, c = t & 3;
    uint4 v = *reinterpret_cast<const uint4*>(tb + row * H_ + h0 + c * 8);
    *reinterpret_cast<uint4*>(&Tl[row * 32 + c * 8]) = v;
  }
  for (int n = tid; n < NWIN; n += 256) widx_l[n] = widx[n];

  float mx = -1e30f;
  for (int n = tid; n < NWIN; n += 256) {
    float v = scores[b * NWIN + n];
    attn_l[n] = v;
    mx = fmaxf(mx, v);
  }
#pragma unroll
  for (int off = 32; off > 0; off >>= 1) mx = fmaxf(mx, __shfl_xor(mx, off, 64));
  if (lane == 0) wredM[wid] = mx;
  __syncthreads();   // also covers Tl / widx_l / attn_l staging
  mx = fmaxf(fmaxf(wredM[0], wredM[1]), fmaxf(wredM[2], wredM[3]));
  float sum = 0.f;
  for (int n = tid; n < NWIN; n += 256) {
    float e = __expf(attn_l[n] - mx);
    attn_l[n] = e;
    sum += e;
  }
#pragma unroll
  for (int off = 32; off > 0; off >>= 1) sum += __shfl_xor(sum, off, 64);
  if (lane == 0) wredS[wid] = sum;
  __syncthreads();
  float inv = 1.f / (wredS[0] + wredS[1] + wredS[2] + wredS[3]);

  int h = tid & 31, g = tid >> 5;   // 8 groups x 252 windows
  float acc = 0.f;
  for (int n = g * 252; n < g * 252 + 252; ++n) {
    int pk = widx_l[n];
    int s = pk & 63, e2 = (pk >> 6) & 63, lv = pk >> 12;
    float va = bf2f(Tl[((lv - 1) * 64 + s) * 32 + h]);
    float vb = bf2f(Tl[((lv - 1) * 64 + e2) * 32 + h]);
    acc += attn_l[n] * fmaxf(va, vb);
  }
  red[g][h] = acc;
  __syncthreads();
  if (tid < 32) {
    float s2 = 0.f;
#pragma unroll
    for (int g2 = 0; g2 < 8; ++g2) s2 += red[g2][tid];
    out[b * H_ + h0 + tid] = s2 * inv;
  }
}

// ---------------- launch ----------------
extern "C" void kernel_launch(void* const* d_in, const int* in_sizes, int n_in,
                              void* d_out, int out_size, void* d_ws, size_t ws_size,
                              hipStream_t stream) {
  const float* lstm = (const float*)d_in[0];
  const float* W1   = (const float*)d_in[1];
  const float* b1   = (const float*)d_in[2];
  const float* W2   = (const float*)d_in[3];
  // d_in[4] = b2: constant shift before softmax -> no effect, unused.
  float* out = (float*)d_out;

  char* ws = (char*)d_ws;
  // layout: widx16 [0,4096) | w1t bf16 [4096, 135168) | table bf16 (14.7MB)
  //         | scores (258048)
  u16*   widx   = (u16*)(ws + 0);
  u16*   w1t    = (u16*)(ws + 4096);
  u16*   table  = (u16*)(ws + 135168);
  float* scores = (float*)(ws + 14815232);

  k01_init <<<288, 256, 0, stream>>>(lstm, W1, table, w1t, widx);
  k2_scores<<<dim3(21, B_), 256, 0, stream>>>(table, w1t, b1, W2, widx, scores);
  k34_out  <<<dim3(16, B_), 256, 0, stream>>>(table, scores, widx, out);
}